// Round 10
// baseline (433.165 us; speedup 1.0000x reference)
//
#include <hip/hip_runtime.h>

#define N_NODES 25000
#define N_EDGES 400000
#define NHALF   12500   // N_NODES/2: thread handles node n and n+NHALF in k_gru

// ---------------- fast transcendentals (fp32, ~2ulp) ----------------
__device__ __forceinline__ float fast_sigmoid(float x) {
    return __builtin_amdgcn_rcpf(1.0f + __expf(-x));
}
__device__ __forceinline__ float fast_tanh(float x) {
    return 1.0f - 2.0f * __builtin_amdgcn_rcpf(__expf(2.0f * x) + 1.0f);
}

// lane j receives value from lane j^k within its 32-lane half (k<16 keeps it
// inside the 16-lane node group). BitMode offset = (xor<<10)|(or<<5)|and.
#define SWZF(x, k) __int_as_float(__builtin_amdgcn_ds_swizzle(__float_as_int(x), ((k) << 10) | 0x1F))
// runtime broadcast: lane gets x from lane (addr>>2); addr = ((lane&0x30)|t)<<2
#define BPERM(x, a) __int_as_float(__builtin_amdgcn_ds_bpermute((a), __float_as_int(x)))

// ---------------- K1: hidden0 = nf @ W_init + b_init ; copy; zero cnt/rcnt ---
__global__ void __launch_bounds__(256) k_init(
        const float* __restrict__ nf, const float* __restrict__ Wini,
        const float* __restrict__ bini,
        float* __restrict__ hidden0, float* __restrict__ hid,
        int* __restrict__ cnt, int* __restrict__ rcnt)
{
    int gtid = blockIdx.x * 256 + threadIdx.x;
    if (gtid <= N_NODES) { cnt[gtid] = 0; rcnt[gtid] = 0; }
    int node = gtid >> 4;
    int j = gtid & 15;
    if (node >= N_NODES) return;

    const float4* nf4 = (const float4*)(nf + node * 32);
    float acc = bini[j];
#pragma unroll
    for (int g = 0; g < 8; ++g) {
        float4 v = nf4[g];
        acc = fmaf(v.x, Wini[(g*4+0)*16 + j], acc);
        acc = fmaf(v.y, Wini[(g*4+1)*16 + j], acc);
        acc = fmaf(v.z, Wini[(g*4+2)*16 + j], acc);
        acc = fmaf(v.w, Wini[(g*4+3)*16 + j], acc);
    }
    hidden0[node*16 + j] = acc;
    hid[node*16 + j] = acc;
}

// ---------------- K2a: rank pass (histogram + within-bucket rank) ----------
__global__ void __launch_bounds__(256) k_rank(const int* __restrict__ send,
        const int* __restrict__ recv,
        int* __restrict__ cnt, int* __restrict__ rcnt,
        int* __restrict__ rank_s, int* __restrict__ rank_r)
{
    int e = blockIdx.x * 256 + threadIdx.x;
    if (e < N_EDGES) {
        rank_s[e] = atomicAdd(&cnt[send[e]], 1);
        rank_r[e] = atomicAdd(&rcnt[recv[e]], 1);
    }
}

// Two independent exclusive scans, one per block (LDS-staged, coalesced I/O).
#define SCAN_TOT 25600                      // 1024 * 25
__global__ void __launch_bounds__(1024) k_scan2(
        const int* __restrict__ cnt,  int* __restrict__ row_ptr,
        const int* __restrict__ rcnt, int* __restrict__ rrow_ptr,
        float* __restrict__ out)
{
    __shared__ int data[SCAN_TOT];          // 100 KB
    __shared__ int sums[1024];              // 4 KB
    int t = threadIdx.x;
    const int CH = 25;

    const int* SRC = blockIdx.x ? rcnt : cnt;
    int* DST = blockIdx.x ? rrow_ptr : row_ptr;

    for (int i = t; i < SCAN_TOT; i += 1024)
        data[i] = (i < N_NODES) ? SRC[i] : 0;
    __syncthreads();

    int base = t * CH;
    int s = 0;
#pragma unroll
    for (int i = 0; i < CH; ++i) s += data[base + i];
    sums[t] = s;
    __syncthreads();

    for (int off = 1; off < 1024; off <<= 1) {
        int add = (t >= off) ? sums[t - off] : 0;
        __syncthreads();
        sums[t] += add;
        __syncthreads();
    }
    int run = sums[t] - s;

#pragma unroll
    for (int i = 0; i < CH; ++i) {
        int v = data[base + i];
        data[base + i] = run;
        run += v;
    }
    __syncthreads();

    for (int i = t; i < N_NODES; i += 1024)
        DST[i] = data[i];
    if (t == 0) {
        if (blockIdx.x == 0) { row_ptr[N_NODES] = N_EDGES; out[0] = 0.0f; }
        else                 { rrow_ptr[N_NODES] = N_EDGES; }
    }
}

// ---------------- K2b: placement + feature permute, ZERO atomics ------------
// pos = row_ptr[send]+rank_s  (sender-CSR slot of edge e)
// rp[pos] = rrow_ptr[recv]+rank_r (receiver-CSR slot) -> k_msg store order
// efp[pos,:] = ef[e,:]  (sequential line read, scattered line store --
// fire-and-forget; replaces the separate 6.4M-thread k_permute gather pass)
__global__ void __launch_bounds__(256) k_place(const int* __restrict__ send,
        const int* __restrict__ recv,
        const int* __restrict__ rank_s, const int* __restrict__ rank_r,
        const int* __restrict__ row_ptr, const int* __restrict__ rrow_ptr,
        const float* __restrict__ ef, float* __restrict__ efp,
        int* __restrict__ rp)
{
    int e = blockIdx.x * 256 + threadIdx.x;
    if (e < N_EDGES) {
        int pos = row_ptr[send[e]] + rank_s[e];
        rp[pos] = rrow_ptr[recv[e]] + rank_r[e];
        const float4* src = (const float4*)(ef + (size_t)e * 16);
        float4* dst = (float4*)(efp + (size_t)pos * 16);
        float4 a = src[0], b = src[1], c = src[2], d = src[3];
        dst[0] = a; dst[1] = b; dst[2] = c; dst[3] = d;
    }
}

// ---------------- K3: 16 senders per block, efp staged through LDS,
// messages scatter-stored in RECEIVER order (rp) ----------
#define MCHUNK 512
#define MSG16(E0,E1,E2,E3) ( \
    ( fmaf((E0).w,q[3],  fmaf((E0).z,q[2],  fmaf((E0).y,q[1],  fmaf((E0).x,q[0],  qb)))) \
    + fmaf((E1).w,q[7],  fmaf((E1).z,q[6],  fmaf((E1).y,q[5],  fmaf((E1).x,q[4],  0.0f)))) ) \
  + ( fmaf((E2).w,q[11], fmaf((E2).z,q[10], fmaf((E2).y,q[9],  fmaf((E2).x,q[8],  0.0f)))) \
    + fmaf((E3).w,q[15], fmaf((E3).z,q[14], fmaf((E3).y,q[13], fmaf((E3).x,q[12], 0.0f)))) ) )

__global__ void __launch_bounds__(256) k_msg(
        const float* __restrict__ hid, const float* __restrict__ efp,
        const int* __restrict__ rp,
        const float* __restrict__ We, const float* __restrict__ be,
        const int* __restrict__ row_ptr,
        float* __restrict__ tmp)
{
    __shared__ float sef[MCHUNK * 16];          // 32 KB
    __shared__ int   srp[MCHUNK];               // 2 KB
    int tid = threadIdx.x;
    int grp = tid >> 4;
    int m   = tid & 15;
    int s   = blockIdx.x * 16 + grp;
    bool active = (s < N_NODES);
    int sc = active ? s : 0;

    int s0 = blockIdx.x * 16;
    int blk_beg = row_ptr[s0];
    int s1 = s0 + 16; if (s1 > N_NODES) s1 = N_NODES;
    int blk_end = row_ptr[s1];

    int beg = active ? row_ptr[s]     : 0;
    int end = active ? row_ptr[s + 1] : 0;

    float h[16];
    {
        const float4* h4 = (const float4*)(hid + sc*16);
        float4 a = h4[0], b = h4[1], c = h4[2], d = h4[3];
        h[0]=a.x; h[1]=a.y; h[2]=a.z;  h[3]=a.w;
        h[4]=b.x; h[5]=b.y; h[6]=b.z;  h[7]=b.w;
        h[8]=c.x; h[9]=c.y; h[10]=c.z; h[11]=c.w;
        h[12]=d.x; h[13]=d.y; h[14]=d.z; h[15]=d.w;
    }
    float q[16];
#pragma unroll
    for (int f = 0; f < 16; ++f) {
        const float4* wf = (const float4*)(We + f*256 + m*16);
        float4 a = wf[0], b = wf[1], c = wf[2], d = wf[3];
        float acc;
        acc  = a.x*h[0]  + a.y*h[1]  + a.z*h[2]  + a.w*h[3];
        acc += b.x*h[4]  + b.y*h[5]  + b.z*h[6]  + b.w*h[7];
        acc += c.x*h[8]  + c.y*h[9]  + c.z*h[10] + c.w*h[11];
        acc += d.x*h[12] + d.y*h[13] + d.z*h[14] + d.w*h[15];
        q[f] = acc;
    }
    float qb;
    {
        const float4* bf = (const float4*)(be + m*16);
        float4 a = bf[0], b = bf[1], c = bf[2], d = bf[3];
        qb  = a.x*h[0]  + a.y*h[1]  + a.z*h[2]  + a.w*h[3];
        qb += b.x*h[4]  + b.y*h[5]  + b.z*h[6]  + b.w*h[7];
        qb += c.x*h[8]  + c.y*h[9]  + c.z*h[10] + c.w*h[11];
        qb += d.x*h[12] + d.y*h[13] + d.z*h[14] + d.w*h[15];
    }

    for (int cbeg = blk_beg; cbeg < blk_end; cbeg += MCHUNK) {
        int cend = cbeg + MCHUNK; if (cend > blk_end) cend = blk_end;
        int nedge = cend - cbeg;
        int nfl = nedge * 4;
        __syncthreads();
        {
            const float4* gsrc = (const float4*)(efp + (size_t)cbeg * 16);
            float4* ldst = (float4*)sef;
            for (int i = tid; i < nfl; i += 256) ldst[i] = gsrc[i];
            for (int i = tid; i < nedge; i += 256) srp[i] = rp[cbeg + i];
        }
        __syncthreads();

        int lo = beg > cbeg ? beg : cbeg;
        int hi = end < cend ? end : cend;
        int i = lo;
        for (; i + 2 <= hi; i += 2) {
            const float4* l0 = (const float4*)(sef + (size_t)(i   - cbeg) * 16);
            const float4* l1 = (const float4*)(sef + (size_t)(i+1 - cbeg) * 16);
            float4 A0=l0[0], A1=l0[1], A2=l0[2], A3=l0[3];
            float4 B0=l1[0], B1=l1[1], B2=l1[2], B3=l1[3];
            int r0 = srp[i   - cbeg];
            int r1 = srp[i+1 - cbeg];
            float v0 = MSG16(A0, A1, A2, A3);
            float v1 = MSG16(B0, B1, B2, B3);
            tmp[(size_t)r0*16 + m] = v0;
            tmp[(size_t)r1*16 + m] = v1;
        }
        for (; i < hi; ++i) {
            const float4* l0 = (const float4*)(sef + (size_t)(i - cbeg) * 16);
            float4 A0=l0[0], A1=l0[1], A2=l0[2], A3=l0[3];
            int r0 = srp[i - cbeg];
            tmp[(size_t)r0*16 + m] = MSG16(A0, A1, A2, A3);
        }
    }
}

// streaming gather: node's in-edge messages are contiguous (receiver-CSR)
__device__ __forceinline__ float gather16(const float* __restrict__ tmp,
        const int* __restrict__ rrow_ptr, int node, int j)
{
    int beg = rrow_ptr[node];
    int end = rrow_ptr[node + 1];
    const float* p = tmp + (size_t)beg * 16 + j;
    int d = end - beg;
    float s0 = 0.0f, s1 = 0.0f, s2 = 0.0f, s3 = 0.0f;
    int i = 0;
    for (; i + 8 <= d; i += 8) {
        float a0 = p[(i+0)*16];
        float a1 = p[(i+1)*16];
        float a2 = p[(i+2)*16];
        float a3 = p[(i+3)*16];
        float a4 = p[(i+4)*16];
        float a5 = p[(i+5)*16];
        float a6 = p[(i+6)*16];
        float a7 = p[(i+7)*16];
        s0 += a0; s1 += a1; s2 += a2; s3 += a3;
        s0 += a4; s1 += a5; s2 += a6; s3 += a7;
    }
    for (; i < d; ++i) s0 += p[i*16];
    return (s0 + s1) + (s2 + s3);
}

// ---------------- K4: 2-node GRU (T=32), dual independent chains -----------
// Thread = unit j of nodes nA and nB=nA+NHALF. Weight regs (48) are SHARED;
// each dependent chain (swizzle->FMA->transcendental->hn) gets an independent
// twin, doubling per-wave ILP in the latency-bound recurrence (VALUBusy 51%
// with 1 node). t-loop rolled (unroll 1) for I-cache; per-step input
// broadcast via runtime ds_bpermute (index (lane&0x30)|t).
__global__ void __launch_bounds__(256) k_gru(
        const float* __restrict__ hid_in, const float* __restrict__ tmp,
        const int* __restrict__ rrow_ptr,
        const float* __restrict__ Wi, const float* __restrict__ Wh,
        const float* __restrict__ bi, const float* __restrict__ bh,
        float* __restrict__ hid_out)
{
    int gtid = blockIdx.x * 256 + threadIdx.x;
    int nA = gtid >> 4;
    int j = gtid & 15;
    if (nA >= NHALF) return;
    int nB = nA + NHALF;

    float msgA = gather16(tmp, rrow_ptr, nA, j);
    float msgB = gather16(tmp, rrow_ptr, nB, j);
    float hA = hid_in[nA*16 + j];
    float hB = hid_in[nB*16 + j];

    float Wz[16], Wr[16], Wc[16];
#pragma unroll
    for (int k = 0; k < 16; ++k) {
        int l = j ^ k;
        Wz[k] = Wh[l*48 + j];
        Wr[k] = Wh[l*48 + 16 + j];
        Wc[k] = Wh[l*48 + 32 + j];
    }
    float Wiz = Wi[j], Wir = Wi[16+j], Wih = Wi[32+j];
    float cz   = bi[j] + bh[j];
    float cr   = bi[16+j] + bh[16+j];
    float bih_ = bi[32+j];
    float bhh_ = bh[32+j];

    float hnA = 0.0f, hnB = 0.0f;
    int baddr = ((threadIdx.x & 63) & 0x30) << 2;   // group base for bpermute

#define STEPK2(k) { \
        float vA = SWZF(hnA, k); float vB = SWZF(hnB, k); \
        azA = fmaf(vA, Wz[k], azA); azB = fmaf(vB, Wz[k], azB); \
        arA = fmaf(vA, Wr[k], arA); arB = fmaf(vB, Wr[k], arB); \
        acA = fmaf(vA, Wc[k], acA); acB = fmaf(vB, Wc[k], acB); }

#define GRUSTEP2(XA, XB) { \
        float azA = fmaf((XA), Wiz, cz),  azB = fmaf((XB), Wiz, cz); \
        float arA = fmaf((XA), Wir, cr),  arB = fmaf((XB), Wir, cr); \
        float acA = bhh_, acB = bhh_; \
        azA = fmaf(hnA, Wz[0], azA); azB = fmaf(hnB, Wz[0], azB); \
        arA = fmaf(hnA, Wr[0], arA); arB = fmaf(hnB, Wr[0], arB); \
        acA = fmaf(hnA, Wc[0], acA); acB = fmaf(hnB, Wc[0], acB); \
        STEPK2(1)  STEPK2(2)  STEPK2(3)  STEPK2(4)  STEPK2(5) \
        STEPK2(6)  STEPK2(7)  STEPK2(8)  STEPK2(9)  STEPK2(10) \
        STEPK2(11) STEPK2(12) STEPK2(13) STEPK2(14) STEPK2(15) \
        float zA = fast_sigmoid(azA), zB = fast_sigmoid(azB); \
        float rA = fast_sigmoid(arA), rB = fast_sigmoid(arB); \
        float hcA = fast_tanh(fmaf((XA), Wih, bih_) + rA * acA); \
        float hcB = fast_tanh(fmaf((XB), Wih, bih_) + rB * acB); \
        hnA = fmaf(zA, hnA - hcA, hcA); \
        hnB = fmaf(zB, hnB - hcB, hcB); }

#pragma unroll 1
    for (int t = 0; t < 16; ++t) {
        int a = baddr + (t << 2);
        float xA = BPERM(hA, a);
        float xB = BPERM(hB, a);
        GRUSTEP2(xA, xB)
    }
#pragma unroll 1
    for (int t = 0; t < 16; ++t) {
        int a = baddr + (t << 2);
        float xA = BPERM(msgA, a);
        float xB = BPERM(msgB, a);
        GRUSTEP2(xA, xB)
    }
#undef GRUSTEP2
#undef STEPK2

    hid_out[nA*16 + j] = hnA;
    hid_out[nB*16 + j] = hnB;
}

// ---------------- K5: readout ----------------
__global__ void __launch_bounds__(256) k_readout(
        const float* __restrict__ hid, const float* __restrict__ hid0,
        const float* __restrict__ Wri, const float* __restrict__ bri,
        const float* __restrict__ Wrj, const float* __restrict__ brj,
        float* __restrict__ out)
{
    int n = blockIdx.x * 256 + threadIdx.x;
    float val = 0.0f;
    if (n < N_NODES) {
        const float4* h4 = (const float4*)(hid + n * 16);
        const float4* g4 = (const float4*)(hid0 + n * 16);
        float iv = bri[0];
        float jv = brj[0];
#pragma unroll
        for (int g = 0; g < 4; ++g) {
            float4 h  = h4[g];
            float4 h0 = g4[g];
            iv = fmaf(h.x,  Wri[g*4+0], iv);  iv = fmaf(h.y,  Wri[g*4+1], iv);
            iv = fmaf(h.z,  Wri[g*4+2], iv);  iv = fmaf(h.w,  Wri[g*4+3], iv);
            iv = fmaf(h0.x, Wri[16+g*4+0], iv); iv = fmaf(h0.y, Wri[16+g*4+1], iv);
            iv = fmaf(h0.z, Wri[16+g*4+2], iv); iv = fmaf(h0.w, Wri[16+g*4+3], iv);
            jv = fmaf(h.x,  Wrj[g*4+0], jv);  jv = fmaf(h.y,  Wrj[g*4+1], jv);
            jv = fmaf(h.z,  Wrj[g*4+2], jv);  jv = fmaf(h.w,  Wrj[g*4+3], jv);
        }
        val = iv * jv;
    }
#pragma unroll
    for (int off = 32; off > 0; off >>= 1)
        val += __shfl_xor(val, off, 64);
    __shared__ float wsum[4];
    int w = threadIdx.x >> 6;
    if ((threadIdx.x & 63) == 0) wsum[w] = val;
    __syncthreads();
    if (threadIdx.x == 0)
        atomicAdd(out, wsum[0] + wsum[1] + wsum[2] + wsum[3]);
}

// ---------------- launch ----------------
extern "C" void kernel_launch(void* const* d_in, const int* in_sizes, int n_in,
                              void* d_out, int out_size, void* d_ws, size_t ws_size,
                              hipStream_t stream)
{
    const float* node_features = (const float*)d_in[0];
    const float* edge_features = (const float*)d_in[1];
    const float* W_init = (const float*)d_in[2];
    const float* b_init = (const float*)d_in[3];
    const float* W_edge = (const float*)d_in[4];
    const float* b_edge = (const float*)d_in[5];
    const float* Wi_gru = (const float*)d_in[6];
    const float* Wh_gru = (const float*)d_in[7];
    const float* bi_gru = (const float*)d_in[8];
    const float* bh_gru = (const float*)d_in[9];
    const float* W_ri = (const float*)d_in[10];
    const float* b_ri = (const float*)d_in[11];
    const float* W_rj = (const float*)d_in[12];
    const float* b_rj = (const float*)d_in[13];
    const int* receivers = (const int*)d_in[14];
    const int* senders   = (const int*)d_in[15];
    float* out = (float*)d_out;

    // workspace carve: floats then ints; ~62 MB total
    float* fb      = (float*)d_ws;
    float* hidden0 = fb;                 // 400000
    float* hidA    = fb + 400000;        // 400000
    float* hidB    = fb + 800000;        // 400000
    float* tmp     = fb + 1200000;       // 6400000 (E*16, RECEIVER-order msgs)
    float* efp     = fb + 7600000;       // 6400000 (E*16, sender-order feats)
    int* ib       = (int*)(fb + 14000000);
    int* cnt      = ib;                  // 25024
    int* row_ptr  = ib + 25024;          // 25024
    int* rcnt     = ib + 50048;          // 25024
    int* rrow_ptr = ib + 75072;          // 25024
    int* rp       = ib + 100096;         // 400000 (sender slot -> receiver slot)
    int* rank_s   = ib + 500096;         // 400000
    int* rank_r   = ib + 900096;         // 400000

    dim3 b256(256);
    int grid_n16 = (N_NODES * 16 + 255) / 256;   // 1563
    int grid_e   = (N_EDGES + 255) / 256;        // 1563
    int grid_n   = (N_NODES + 255) / 256;        // 98
    int grid_blk = (N_NODES + 15) / 16;          // 1563 (16 senders per block)
    int grid_gru = (NHALF * 16 + 255) / 256;     // 782 (2 nodes per thread)

    k_init<<<grid_n16, b256, 0, stream>>>(node_features, W_init, b_init,
                                          hidden0, hidA, cnt, rcnt);
    k_rank<<<grid_e, b256, 0, stream>>>(senders, receivers, cnt, rcnt,
                                        rank_s, rank_r);
    k_scan2<<<2, 1024, 0, stream>>>(cnt, row_ptr, rcnt, rrow_ptr, out);
    k_place<<<grid_e, b256, 0, stream>>>(senders, receivers, rank_s, rank_r,
                                         row_ptr, rrow_ptr,
                                         edge_features, efp, rp);

    float* hin = hidA;
    float* hout = hidB;
    for (int it = 0; it < 3; ++it) {
        k_msg<<<grid_blk, b256, 0, stream>>>(hin, efp, rp,
                                             W_edge, b_edge, row_ptr, tmp);
        k_gru<<<grid_gru, b256, 0, stream>>>(hin, tmp, rrow_ptr,
                                             Wi_gru, Wh_gru, bi_gru, bh_gru, hout);
        float* t = hin; hin = hout; hout = t;
    }

    k_readout<<<grid_n, b256, 0, stream>>>(hin, hidden0, W_ri, b_ri, W_rj, b_rj, out);
}

// Round 11
// 402.468 us; speedup vs baseline: 1.0763x; 1.0763x over previous
//
#include <hip/hip_runtime.h>

#define N_NODES 25000
#define N_EDGES 400000

// ---------------- fast transcendentals (fp32, ~2ulp) ----------------
__device__ __forceinline__ float fast_sigmoid(float x) {
    return __builtin_amdgcn_rcpf(1.0f + __expf(-x));
}
__device__ __forceinline__ float fast_tanh(float x) {
    return 1.0f - 2.0f * __builtin_amdgcn_rcpf(__expf(2.0f * x) + 1.0f);
}

// lane j receives value from lane j^k within its 32-lane half (k<16 keeps it
// inside the 16-lane node group). BitMode offset = (xor<<10)|(or<<5)|and.
#define SWZF(x, k) __int_as_float(__builtin_amdgcn_ds_swizzle(__float_as_int(x), ((k) << 10) | 0x1F))
// broadcast lane t of each 16-lane group: src = (lane & 0x10) | t
#define BCAST16(x, t) __int_as_float(__builtin_amdgcn_ds_swizzle(__float_as_int(x), ((t) << 5) | 0x10))

// ---------------- K1: hidden0 = nf @ W_init + b_init ; copy; zero cnt/rcnt ---
__global__ void __launch_bounds__(256) k_init(
        const float* __restrict__ nf, const float* __restrict__ Wini,
        const float* __restrict__ bini,
        float* __restrict__ hidden0, float* __restrict__ hid,
        int* __restrict__ cnt, int* __restrict__ rcnt)
{
    int gtid = blockIdx.x * 256 + threadIdx.x;
    if (gtid <= N_NODES) { cnt[gtid] = 0; rcnt[gtid] = 0; }
    int node = gtid >> 4;
    int j = gtid & 15;
    if (node >= N_NODES) return;

    const float4* nf4 = (const float4*)(nf + node * 32);
    float acc = bini[j];
#pragma unroll
    for (int g = 0; g < 8; ++g) {
        float4 v = nf4[g];
        acc = fmaf(v.x, Wini[(g*4+0)*16 + j], acc);
        acc = fmaf(v.y, Wini[(g*4+1)*16 + j], acc);
        acc = fmaf(v.z, Wini[(g*4+2)*16 + j], acc);
        acc = fmaf(v.w, Wini[(g*4+3)*16 + j], acc);
    }
    hidden0[node*16 + j] = acc;
    hid[node*16 + j] = acc;
}

// ---------------- K2a: rank pass (histogram + within-bucket rank) ----------
__global__ void __launch_bounds__(256) k_rank(const int* __restrict__ send,
        const int* __restrict__ recv,
        int* __restrict__ cnt, int* __restrict__ rcnt,
        int* __restrict__ rank_s, int* __restrict__ rank_r)
{
    int e = blockIdx.x * 256 + threadIdx.x;
    if (e < N_EDGES) {
        rank_s[e] = atomicAdd(&cnt[send[e]], 1);
        rank_r[e] = atomicAdd(&rcnt[recv[e]], 1);
    }
}

// Two independent exclusive scans, one per block (LDS-staged, coalesced I/O).
#define SCAN_TOT 25600                      // 1024 * 25
__global__ void __launch_bounds__(1024) k_scan2(
        const int* __restrict__ cnt,  int* __restrict__ row_ptr,
        const int* __restrict__ rcnt, int* __restrict__ rrow_ptr,
        float* __restrict__ out)
{
    __shared__ int data[SCAN_TOT];          // 100 KB
    __shared__ int sums[1024];              // 4 KB
    int t = threadIdx.x;
    const int CH = 25;

    const int* SRC = blockIdx.x ? rcnt : cnt;
    int* DST = blockIdx.x ? rrow_ptr : row_ptr;

    for (int i = t; i < SCAN_TOT; i += 1024)
        data[i] = (i < N_NODES) ? SRC[i] : 0;
    __syncthreads();

    int base = t * CH;
    int s = 0;
#pragma unroll
    for (int i = 0; i < CH; ++i) s += data[base + i];
    sums[t] = s;
    __syncthreads();

    for (int off = 1; off < 1024; off <<= 1) {
        int add = (t >= off) ? sums[t - off] : 0;
        __syncthreads();
        sums[t] += add;
        __syncthreads();
    }
    int run = sums[t] - s;

#pragma unroll
    for (int i = 0; i < CH; ++i) {
        int v = data[base + i];
        data[base + i] = run;
        run += v;
    }
    __syncthreads();

    for (int i = t; i < N_NODES; i += 1024)
        DST[i] = data[i];
    if (t == 0) {
        if (blockIdx.x == 0) { row_ptr[N_NODES] = N_EDGES; out[0] = 0.0f; }
        else                 { rrow_ptr[N_NODES] = N_EDGES; }
    }
}

// ---------------- K2b: placement + feature permute, ZERO atomics ------------
// pos = row_ptr[send]+rank_s  (sender-CSR slot of edge e)
// rp[pos] = rrow_ptr[recv]+rank_r (receiver-CSR slot) -> k_msg store order
// efp[pos,:] = ef[e,:]  (sequential line read, scattered line store)
__global__ void __launch_bounds__(256) k_place(const int* __restrict__ send,
        const int* __restrict__ recv,
        const int* __restrict__ rank_s, const int* __restrict__ rank_r,
        const int* __restrict__ row_ptr, const int* __restrict__ rrow_ptr,
        const float* __restrict__ ef, float* __restrict__ efp,
        int* __restrict__ rp)
{
    int e = blockIdx.x * 256 + threadIdx.x;
    if (e < N_EDGES) {
        int pos = row_ptr[send[e]] + rank_s[e];
        rp[pos] = rrow_ptr[recv[e]] + rank_r[e];
        const float4* src = (const float4*)(ef + (size_t)e * 16);
        float4* dst = (float4*)(efp + (size_t)pos * 16);
        float4 a = src[0], b = src[1], c = src[2], d = src[3];
        dst[0] = a; dst[1] = b; dst[2] = c; dst[3] = d;
    }
}

// ---------------- K3: 16 senders per block, efp staged through LDS,
// messages scatter-stored in RECEIVER order (rp) ----------
#define MCHUNK 512
#define MSG16(E0,E1,E2,E3) ( \
    ( fmaf((E0).w,q[3],  fmaf((E0).z,q[2],  fmaf((E0).y,q[1],  fmaf((E0).x,q[0],  qb)))) \
    + fmaf((E1).w,q[7],  fmaf((E1).z,q[6],  fmaf((E1).y,q[5],  fmaf((E1).x,q[4],  0.0f)))) ) \
  + ( fmaf((E2).w,q[11], fmaf((E2).z,q[10], fmaf((E2).y,q[9],  fmaf((E2).x,q[8],  0.0f)))) \
    + fmaf((E3).w,q[15], fmaf((E3).z,q[14], fmaf((E3).y,q[13], fmaf((E3).x,q[12], 0.0f)))) ) )

__global__ void __launch_bounds__(256) k_msg(
        const float* __restrict__ hid, const float* __restrict__ efp,
        const int* __restrict__ rp,
        const float* __restrict__ We, const float* __restrict__ be,
        const int* __restrict__ row_ptr,
        float* __restrict__ tmp)
{
    __shared__ float sef[MCHUNK * 16];          // 32 KB
    __shared__ int   srp[MCHUNK];               // 2 KB
    int tid = threadIdx.x;
    int grp = tid >> 4;
    int m   = tid & 15;
    int s   = blockIdx.x * 16 + grp;
    bool active = (s < N_NODES);
    int sc = active ? s : 0;

    int s0 = blockIdx.x * 16;
    int blk_beg = row_ptr[s0];
    int s1 = s0 + 16; if (s1 > N_NODES) s1 = N_NODES;
    int blk_end = row_ptr[s1];

    int beg = active ? row_ptr[s]     : 0;
    int end = active ? row_ptr[s + 1] : 0;

    float h[16];
    {
        const float4* h4 = (const float4*)(hid + sc*16);
        float4 a = h4[0], b = h4[1], c = h4[2], d = h4[3];
        h[0]=a.x; h[1]=a.y; h[2]=a.z;  h[3]=a.w;
        h[4]=b.x; h[5]=b.y; h[6]=b.z;  h[7]=b.w;
        h[8]=c.x; h[9]=c.y; h[10]=c.z; h[11]=c.w;
        h[12]=d.x; h[13]=d.y; h[14]=d.z; h[15]=d.w;
    }
    float q[16];
#pragma unroll
    for (int f = 0; f < 16; ++f) {
        const float4* wf = (const float4*)(We + f*256 + m*16);
        float4 a = wf[0], b = wf[1], c = wf[2], d = wf[3];
        float acc;
        acc  = a.x*h[0]  + a.y*h[1]  + a.z*h[2]  + a.w*h[3];
        acc += b.x*h[4]  + b.y*h[5]  + b.z*h[6]  + b.w*h[7];
        acc += c.x*h[8]  + c.y*h[9]  + c.z*h[10] + c.w*h[11];
        acc += d.x*h[12] + d.y*h[13] + d.z*h[14] + d.w*h[15];
        q[f] = acc;
    }
    float qb;
    {
        const float4* bf = (const float4*)(be + m*16);
        float4 a = bf[0], b = bf[1], c = bf[2], d = bf[3];
        qb  = a.x*h[0]  + a.y*h[1]  + a.z*h[2]  + a.w*h[3];
        qb += b.x*h[4]  + b.y*h[5]  + b.z*h[6]  + b.w*h[7];
        qb += c.x*h[8]  + c.y*h[9]  + c.z*h[10] + c.w*h[11];
        qb += d.x*h[12] + d.y*h[13] + d.z*h[14] + d.w*h[15];
    }

    for (int cbeg = blk_beg; cbeg < blk_end; cbeg += MCHUNK) {
        int cend = cbeg + MCHUNK; if (cend > blk_end) cend = blk_end;
        int nedge = cend - cbeg;
        int nfl = nedge * 4;
        __syncthreads();
        {
            const float4* gsrc = (const float4*)(efp + (size_t)cbeg * 16);
            float4* ldst = (float4*)sef;
            for (int i = tid; i < nfl; i += 256) ldst[i] = gsrc[i];
            for (int i = tid; i < nedge; i += 256) srp[i] = rp[cbeg + i];
        }
        __syncthreads();

        int lo = beg > cbeg ? beg : cbeg;
        int hi = end < cend ? end : cend;
        int i = lo;
        for (; i + 2 <= hi; i += 2) {
            const float4* l0 = (const float4*)(sef + (size_t)(i   - cbeg) * 16);
            const float4* l1 = (const float4*)(sef + (size_t)(i+1 - cbeg) * 16);
            float4 A0=l0[0], A1=l0[1], A2=l0[2], A3=l0[3];
            float4 B0=l1[0], B1=l1[1], B2=l1[2], B3=l1[3];
            int r0 = srp[i   - cbeg];
            int r1 = srp[i+1 - cbeg];
            float v0 = MSG16(A0, A1, A2, A3);
            float v1 = MSG16(B0, B1, B2, B3);
            tmp[(size_t)r0*16 + m] = v0;
            tmp[(size_t)r1*16 + m] = v1;
        }
        for (; i < hi; ++i) {
            const float4* l0 = (const float4*)(sef + (size_t)(i - cbeg) * 16);
            float4 A0=l0[0], A1=l0[1], A2=l0[2], A3=l0[3];
            int r0 = srp[i - cbeg];
            tmp[(size_t)r0*16 + m] = MSG16(A0, A1, A2, A3);
        }
    }
}

// ---------------- K4: STREAMING gather + GRU (T=32), split-chain ILP --------
// Round-9 structure (16 lanes/node, full unroll, immediate ds_swizzle,
// full wave count) + each gate's 16-term accumulation split into TWO
// independent 8-deep FMA chains (az0/az1 etc.) -> per-step dependent-FMA
// latency halved without costing occupancy (round-10's 2-node version
// halved TLP and regressed; this adds ILP inside the existing wave budget).
__global__ void __launch_bounds__(256) k_gru(
        const float* __restrict__ hid_in, const float* __restrict__ tmp,
        const int* __restrict__ rrow_ptr,
        const float* __restrict__ Wi, const float* __restrict__ Wh,
        const float* __restrict__ bi, const float* __restrict__ bh,
        float* __restrict__ hid_out)
{
    int gtid = blockIdx.x * 256 + threadIdx.x;
    int node = gtid >> 4;
    int j = gtid & 15;
    if (node >= N_NODES) return;

    float s0 = 0.0f, s1 = 0.0f, s2 = 0.0f, s3 = 0.0f;
    {
        int beg = rrow_ptr[node];
        int end = rrow_ptr[node + 1];
        const float* p = tmp + (size_t)beg * 16 + j;
        int d = end - beg;
        int i = 0;
        for (; i + 8 <= d; i += 8) {
            float a0 = p[(i+0)*16];
            float a1 = p[(i+1)*16];
            float a2 = p[(i+2)*16];
            float a3 = p[(i+3)*16];
            float a4 = p[(i+4)*16];
            float a5 = p[(i+5)*16];
            float a6 = p[(i+6)*16];
            float a7 = p[(i+7)*16];
            s0 += a0; s1 += a1; s2 += a2; s3 += a3;
            s0 += a4; s1 += a5; s2 += a6; s3 += a7;
        }
        for (; i < d; ++i) s0 += p[i*16];
    }
    float msg_own = (s0 + s1) + (s2 + s3);
    float h_own = hid_in[node*16 + j];

    float Wz[16], Wr[16], Wc[16];
#pragma unroll
    for (int k = 0; k < 16; ++k) {
        int l = j ^ k;
        Wz[k] = Wh[l*48 + j];
        Wr[k] = Wh[l*48 + 16 + j];
        Wc[k] = Wh[l*48 + 32 + j];
    }
    float Wiz = Wi[j], Wir = Wi[16+j], Wih = Wi[32+j];
    float cz   = bi[j] + bh[j];
    float cr   = bi[16+j] + bh[16+j];
    float bih_ = bi[32+j];
    float bhh_ = bh[32+j];

    float hn = 0.0f;

// two swizzles per macro, even k -> chain0, odd k -> chain1
#define STEPK2(k0, k1) { \
        float va = SWZF(hn, k0); float vb = SWZF(hn, k1); \
        az0 = fmaf(va, Wz[k0], az0); az1 = fmaf(vb, Wz[k1], az1); \
        ar0 = fmaf(va, Wr[k0], ar0); ar1 = fmaf(vb, Wr[k1], ar1); \
        ac0 = fmaf(va, Wc[k0], ac0); ac1 = fmaf(vb, Wc[k1], ac1); }

#define GRUSTEP(XV) { \
        float xv = (XV); \
        float v1 = SWZF(hn, 1); \
        float az0 = fmaf(xv, Wiz, cz); \
        float ar0 = fmaf(xv, Wir, cr); \
        float ac0 = bhh_; \
        az0 = fmaf(hn, Wz[0], az0); \
        ar0 = fmaf(hn, Wr[0], ar0); \
        ac0 = fmaf(hn, Wc[0], ac0); \
        float az1 = v1 * Wz[1]; \
        float ar1 = v1 * Wr[1]; \
        float ac1 = v1 * Wc[1]; \
        STEPK2(2,3)   STEPK2(4,5)   STEPK2(6,7) \
        STEPK2(8,9)   STEPK2(10,11) STEPK2(12,13) \
        STEPK2(14,15) \
        float z  = fast_sigmoid(az0 + az1); \
        float r  = fast_sigmoid(ar0 + ar1); \
        float hc = fast_tanh(fmaf(xv, Wih, bih_) + r * (ac0 + ac1)); \
        hn = fmaf(z, hn - hc, hc); }

    // t = 0..15: x_t = hidden[node][t]
    GRUSTEP(BCAST16(h_own, 0))  GRUSTEP(BCAST16(h_own, 1))
    GRUSTEP(BCAST16(h_own, 2))  GRUSTEP(BCAST16(h_own, 3))
    GRUSTEP(BCAST16(h_own, 4))  GRUSTEP(BCAST16(h_own, 5))
    GRUSTEP(BCAST16(h_own, 6))  GRUSTEP(BCAST16(h_own, 7))
    GRUSTEP(BCAST16(h_own, 8))  GRUSTEP(BCAST16(h_own, 9))
    GRUSTEP(BCAST16(h_own, 10)) GRUSTEP(BCAST16(h_own, 11))
    GRUSTEP(BCAST16(h_own, 12)) GRUSTEP(BCAST16(h_own, 13))
    GRUSTEP(BCAST16(h_own, 14)) GRUSTEP(BCAST16(h_own, 15))
    // t = 16..31: x_t = messages[node][t-16]
    GRUSTEP(BCAST16(msg_own, 0))  GRUSTEP(BCAST16(msg_own, 1))
    GRUSTEP(BCAST16(msg_own, 2))  GRUSTEP(BCAST16(msg_own, 3))
    GRUSTEP(BCAST16(msg_own, 4))  GRUSTEP(BCAST16(msg_own, 5))
    GRUSTEP(BCAST16(msg_own, 6))  GRUSTEP(BCAST16(msg_own, 7))
    GRUSTEP(BCAST16(msg_own, 8))  GRUSTEP(BCAST16(msg_own, 9))
    GRUSTEP(BCAST16(msg_own, 10)) GRUSTEP(BCAST16(msg_own, 11))
    GRUSTEP(BCAST16(msg_own, 12)) GRUSTEP(BCAST16(msg_own, 13))
    GRUSTEP(BCAST16(msg_own, 14)) GRUSTEP(BCAST16(msg_own, 15))
#undef GRUSTEP
#undef STEPK2

    hid_out[node*16 + j] = hn;
}

// ---------------- K5: readout ----------------
__global__ void __launch_bounds__(256) k_readout(
        const float* __restrict__ hid, const float* __restrict__ hid0,
        const float* __restrict__ Wri, const float* __restrict__ bri,
        const float* __restrict__ Wrj, const float* __restrict__ brj,
        float* __restrict__ out)
{
    int n = blockIdx.x * 256 + threadIdx.x;
    float val = 0.0f;
    if (n < N_NODES) {
        const float4* h4 = (const float4*)(hid + n * 16);
        const float4* g4 = (const float4*)(hid0 + n * 16);
        float iv = bri[0];
        float jv = brj[0];
#pragma unroll
        for (int g = 0; g < 4; ++g) {
            float4 h  = h4[g];
            float4 h0 = g4[g];
            iv = fmaf(h.x,  Wri[g*4+0], iv);  iv = fmaf(h.y,  Wri[g*4+1], iv);
            iv = fmaf(h.z,  Wri[g*4+2], iv);  iv = fmaf(h.w,  Wri[g*4+3], iv);
            iv = fmaf(h0.x, Wri[16+g*4+0], iv); iv = fmaf(h0.y, Wri[16+g*4+1], iv);
            iv = fmaf(h0.z, Wri[16+g*4+2], iv); iv = fmaf(h0.w, Wri[16+g*4+3], iv);
            jv = fmaf(h.x,  Wrj[g*4+0], jv);  jv = fmaf(h.y,  Wrj[g*4+1], jv);
            jv = fmaf(h.z,  Wrj[g*4+2], jv);  jv = fmaf(h.w,  Wrj[g*4+3], jv);
        }
        val = iv * jv;
    }
#pragma unroll
    for (int off = 32; off > 0; off >>= 1)
        val += __shfl_xor(val, off, 64);
    __shared__ float wsum[4];
    int w = threadIdx.x >> 6;
    if ((threadIdx.x & 63) == 0) wsum[w] = val;
    __syncthreads();
    if (threadIdx.x == 0)
        atomicAdd(out, wsum[0] + wsum[1] + wsum[2] + wsum[3]);
}

// ---------------- launch ----------------
extern "C" void kernel_launch(void* const* d_in, const int* in_sizes, int n_in,
                              void* d_out, int out_size, void* d_ws, size_t ws_size,
                              hipStream_t stream)
{
    const float* node_features = (const float*)d_in[0];
    const float* edge_features = (const float*)d_in[1];
    const float* W_init = (const float*)d_in[2];
    const float* b_init = (const float*)d_in[3];
    const float* W_edge = (const float*)d_in[4];
    const float* b_edge = (const float*)d_in[5];
    const float* Wi_gru = (const float*)d_in[6];
    const float* Wh_gru = (const float*)d_in[7];
    const float* bi_gru = (const float*)d_in[8];
    const float* bh_gru = (const float*)d_in[9];
    const float* W_ri = (const float*)d_in[10];
    const float* b_ri = (const float*)d_in[11];
    const float* W_rj = (const float*)d_in[12];
    const float* b_rj = (const float*)d_in[13];
    const int* receivers = (const int*)d_in[14];
    const int* senders   = (const int*)d_in[15];
    float* out = (float*)d_out;

    // workspace carve: floats then ints; ~62 MB total
    float* fb      = (float*)d_ws;
    float* hidden0 = fb;                 // 400000
    float* hidA    = fb + 400000;        // 400000
    float* hidB    = fb + 800000;        // 400000
    float* tmp     = fb + 1200000;       // 6400000 (E*16, RECEIVER-order msgs)
    float* efp     = fb + 7600000;       // 6400000 (E*16, sender-order feats)
    int* ib       = (int*)(fb + 14000000);
    int* cnt      = ib;                  // 25024
    int* row_ptr  = ib + 25024;          // 25024
    int* rcnt     = ib + 50048;          // 25024
    int* rrow_ptr = ib + 75072;          // 25024
    int* rp       = ib + 100096;         // 400000 (sender slot -> receiver slot)
    int* rank_s   = ib + 500096;         // 400000
    int* rank_r   = ib + 900096;         // 400000

    dim3 b256(256);
    int grid_n16 = (N_NODES * 16 + 255) / 256;   // 1563
    int grid_e   = (N_EDGES + 255) / 256;        // 1563
    int grid_n   = (N_NODES + 255) / 256;        // 98
    int grid_blk = (N_NODES + 15) / 16;          // 1563 (16 senders per block)

    k_init<<<grid_n16, b256, 0, stream>>>(node_features, W_init, b_init,
                                          hidden0, hidA, cnt, rcnt);
    k_rank<<<grid_e, b256, 0, stream>>>(senders, receivers, cnt, rcnt,
                                        rank_s, rank_r);
    k_scan2<<<2, 1024, 0, stream>>>(cnt, row_ptr, rcnt, rrow_ptr, out);
    k_place<<<grid_e, b256, 0, stream>>>(senders, receivers, rank_s, rank_r,
                                         row_ptr, rrow_ptr,
                                         edge_features, efp, rp);

    float* hin = hidA;
    float* hout = hidB;
    for (int it = 0; it < 3; ++it) {
        k_msg<<<grid_blk, b256, 0, stream>>>(hin, efp, rp,
                                             W_edge, b_edge, row_ptr, tmp);
        k_gru<<<grid_n16, b256, 0, stream>>>(hin, tmp, rrow_ptr,
                                             Wi_gru, Wh_gru, bi_gru, bh_gru, hout);
        float* t = hin; hin = hout; hout = t;
    }

    k_readout<<<grid_n, b256, 0, stream>>>(hin, hidden0, W_ri, b_ri, W_rj, b_rj, out);
}